// Round 3
// baseline (384.394 us; speedup 1.0000x reference)
//
#include <hip/hip_runtime.h>

typedef __attribute__((ext_vector_type(8))) short short8;
typedef __attribute__((ext_vector_type(4))) float f32x4;
typedef __attribute__((ext_vector_type(2))) unsigned int u32x2;

#define TTOK 10000

__device__ __forceinline__ unsigned pkbf(float lo, float hi){
  unsigned r;
  asm("v_cvt_pk_bf16_f32 %0, %1, %2" : "=v"(r) : "v"(lo), "v"(hi));
  return r;
}

__device__ __forceinline__ unsigned short f2b(float f){
  unsigned x = __float_as_uint(f);
  unsigned r = (x + 0x7fffu + ((x>>16)&1u)) >> 16; // RNE
  return (unsigned short)r;
}

// ---------------- prep: bf16 weights, hb+t*tw seeds, c vector ----------------
__global__ void cnf_prep(const float* __restrict__ h, const float* __restrict__ Wx,
                         const float* __restrict__ wxt, const float* __restrict__ bx,
                         const float* __restrict__ Wh, const float* __restrict__ wht,
                         const float* __restrict__ bh, const float* __restrict__ W2,
                         float* __restrict__ hbt, float* __restrict__ cv,
                         unsigned short* __restrict__ wxb, unsigned short* __restrict__ w2b)
{
  const int b = blockIdx.x, t = threadIdx.x;
  if (b < 8) {
    for (int i=0;i<8;++i){ int idx = b*2048 + i*256 + t; wxb[idx] = f2b(Wx[idx]); }
  } else if (b < 16) {
    for (int i=0;i<8;++i){ int idx = (b-8)*2048 + i*256 + t; w2b[idx] = f2b(W2[idx]); }
  } else if (b < 18) {
    for (int i=0;i<4;++i){
      int idx = i*256 + t;
      int sb = (b-16)*8 + (idx>>7);
      int j  = idx & 127;
      float a = 0.f;
      for (int e2=0;e2<128;++e2) a += h[sb*128+e2]*Wh[j*128+e2];
      float base = a + bh[j] + bx[j];
      float tw   = wxt[j] + wht[j];
      for (int ti=0; ti<5; ++ti)
        hbt[(ti*16+sb)*128 + j] = base + 0.25f*(float)ti*tw;   // t in {0,.25,.5,.75,1}
    }
  } else {
    if (t < 128){
      float a = 0.f;
      for (int i=0;i<128;++i) a += W2[i*128+t]*Wx[t*128+i];
      cv[t] = a;
    }
  }
}

// ---------------- fused CNF main kernel ----------------
// Block: 256 thr = 4 waves; wave handles 16 rows (one 16-wide N-tile).
// Transposed MFMA formulation: preT[h,m] = sum_e Wx[h,e]*zT[e,m] (A=Wx, B=zT).
// launch_bounds(256,1): round-2 lesson — (256,2) made the allocator stop at
// 128 VGPR and spill ~1KB/thread (637 MB scratch writes). ~180 VGPR still
// gives 2 waves/SIMD; LDS (78KB) caps at 2 blocks/CU anyway.
__global__ __launch_bounds__(256, 1) void cnf_main(
    const float* __restrict__ emb, const float* __restrict__ lp0,
    const float* __restrict__ b2g, const float* __restrict__ hbt,
    const float* __restrict__ cg,  const unsigned short* __restrict__ wxb,
    const unsigned short* __restrict__ w2b, float* __restrict__ out)
{
  __shared__ __align__(16) unsigned short sWx[16384];
  __shared__ __align__(16) unsigned short sW2[16384];
  __shared__ __align__(16) float sC[128];
  __shared__ __align__(16) float sB2[128];
  __shared__ __align__(16) float sH[5*2*128];            // hb+t*tw slices for block's <=2 sb values
  __shared__ __align__(16) unsigned short sT[4][1024];   // per-wave transpose buf (2KB)

  const int tid = threadIdx.x;
  const int rowbase = blockIdx.x*64;
  const int sb0 = rowbase/TTOK, sb1 = (rowbase+63)/TTOK;

  // stage weights into LDS with XOR swizzle (row&7)<<4 to kill b128-read bank conflicts
  for (int it=0; it<8; ++it){
    int L = it*4096 + tid*16;          // byte offset, 16B chunk inside one 256B row
    int hrow = L >> 8;
    int dst = L ^ ((hrow&7)<<4);
    *(int4*)((char*)sWx + dst) = *(const int4*)((const char*)wxb + L);
    *(int4*)((char*)sW2 + dst) = *(const int4*)((const char*)w2b + L);
  }
  if (tid < 128) sC[tid] = cg[tid]; else sB2[tid-128] = b2g[tid-128];
  for (int idx = tid; idx < 1280; idx += 256){
    int ti = idx >> 8, r = idx & 255;
    int j = r >> 7, e = r & 127;
    int sb = j ? sb1 : sb0;
    sH[idx] = hbt[(ti*16 + sb)*128 + e];
  }
  __syncthreads();

  const int w = tid>>6, l = tid&63, q = l&15, g = l>>4;
  unsigned short* tb = &sT[w][0];
  const int cw  = q*8 + 4*(g&1) + 128*(g>>1); // transpose write base (ushort idx), + htl*256
  const int cr  = g*128 + q*8;                // transpose read base, + kcl*512
  const int wsw = (q&7)<<4;                   // weight-read swizzle
  const int qg  = q*256 + g*16;               // weight-read lane offset (bytes)

  const int row = rowbase + 16*w + q;
  const int sb  = row/TTOK, tt = row - sb*TTOK;
  const int hsel = (sb == sb0) ? 0 : 128;

  f32x4 zb[8], ks[8], wk[8];
  float dlt = 0.f;

  // z0 = emb[t] into fp32 C-layout masters (slot e = 16*ht+4*g+r, col q)
  #pragma unroll
  for (int ht=0; ht<8; ++ht){
    zb[ht] = *(const f32x4*)(emb + tt*128 + 16*ht + 4*g);
    wk[ht] = (f32x4){0.f,0.f,0.f,0.f};
    ks[ht] = (f32x4){0.f,0.f,0.f,0.f};
  }

  #pragma unroll 1
  for (int se=0; se<8; ++se){
    const int   s    = se>>2, e = se&3;
    const float coef = (e==0)?0.f:((e==3)?0.5f:0.25f); // z_eval = z_base + coef*k_prev
    const float we   = (e==1||e==2)?2.f:1.f;
    const int   ti   = 2*s + ((e==0)?0:((e<3)?1:2));

    // ---- pack z_eval -> LDS transpose -> bf16 B-frags
    short8 zfr[4];
    #pragma unroll
    for (int hf=0; hf<2; ++hf){
      #pragma unroll
      for (int htl=0; htl<4; ++htl){
        const int ht = 4*hf + htl;
        float v0 = zb[ht][0] + coef*wk[ht][0];
        float v1 = zb[ht][1] + coef*wk[ht][1];
        float v2 = zb[ht][2] + coef*wk[ht][2];
        float v3 = zb[ht][3] + coef*wk[ht][3];
        u32x2 wv = { pkbf(v0,v1), pkbf(v2,v3) };
        *(u32x2*)&tb[htl*256 + cw] = wv;
      }
      #pragma unroll
      for (int kcl=0; kcl<2; ++kcl)
        zfr[2*hf+kcl] = *(const short8*)&tb[kcl*512 + cr];
    }

    // ---- seed acc with hb + t*tw (LDS slice)
    {
      const float* hb = &sH[ti*256 + hsel + 4*g];
      #pragma unroll
      for (int ht=0; ht<8; ++ht)
        wk[ht] = *(const f32x4*)(hb + 16*ht);
    }

    // ---- matmul1: pre = Wx . zT
    #pragma unroll
    for (int kc=0; kc<4; ++kc){
      #pragma unroll
      for (int ht=0; ht<8; ++ht){
        const int off = (ht*4096 + kc*64 + qg) ^ wsw;
        short8 af = *(const short8*)((const char*)sWx + off);
        wk[ht] = __builtin_amdgcn_mfma_f32_16x16x32_bf16(af, zfr[kc], wk[ht], 0,0,0);
      }
    }

    // ---- elementwise: softplus -> bf16 frags (via LDS transpose), sigmoid*c -> div
    short8 sfr[4];
    float dv = 0.f;
    #pragma unroll
    for (int hf=0; hf<2; ++hf){
      #pragma unroll
      for (int htl=0; htl<4; ++htl){
        const int ht = 4*hf+htl;
        f32x4 cc = *(const f32x4*)(&sC[16*ht + 4*g]);
        float spv[4];
        #pragma unroll
        for (int r=0;r<4;++r){
          float x  = wk[ht][r];
          float ax = __builtin_fabsf(x);
          float ea = __expf(-ax);
          float opa = 1.0f + ea;
          float rc = __builtin_amdgcn_rcpf(opa);
          float lg = __logf(opa);
          spv[r] = fmaxf(x,0.f) + lg;                 // softplus
          float sg = (x >= 0.f) ? rc : ea*rc;         // sigmoid
          dv += sg*cc[r];
        }
        u32x2 wv = { pkbf(spv[0],spv[1]), pkbf(spv[2],spv[3]) };
        *(u32x2*)&tb[htl*256 + cw] = wv;
      }
      #pragma unroll
      for (int kcl=0; kcl<2; ++kcl)
        sfr[2*hf+kcl] = *(const short8*)&tb[kcl*512 + cr];
    }
    dlt += we*dv;

    // ---- matmul2: dz = W2 . spT  (acc seeded with b2)
    #pragma unroll
    for (int ot=0; ot<8; ++ot)
      wk[ot] = *(const f32x4*)(&sB2[16*ot + 4*g]);
    #pragma unroll
    for (int kc=0; kc<4; ++kc){
      #pragma unroll
      for (int ot=0; ot<8; ++ot){
        const int off = (ot*4096 + kc*64 + qg) ^ wsw;
        short8 af = *(const short8*)((const char*)sW2 + off);
        wk[ot] = __builtin_amdgcn_mfma_f32_16x16x32_bf16(af, sfr[kc], wk[ot], 0,0,0);
      }
    }

    // ---- RK4 accumulate (wk now holds k_e; also feeds next eval's z_eval)
    if (e==0){
      #pragma unroll
      for (int ht=0;ht<8;++ht) ks[ht] = wk[ht];
    } else {
      #pragma unroll
      for (int ht=0;ht<8;++ht) ks[ht] += we*wk[ht];
    }
    if (e==3){
      #pragma unroll
      for (int ht=0;ht<8;++ht) zb[ht] += (1.f/12.f)*ks[ht];
    }
  }

  // ---- epilogue: reduce div partials over the 4 g-lanes, write log_pz1
  {
    float d = dlt*(1.f/12.f);
    d += __shfl_xor(d, 16, 64);
    d += __shfl_xor(d, 32, 64);
    if (g==0) out[row] = lp0[row] - d;
  }
}

extern "C" void kernel_launch(void* const* d_in, const int* in_sizes, int n_in,
                              void* d_out, int out_size, void* d_ws, size_t ws_size,
                              hipStream_t stream) {
  const float* h    = (const float*)d_in[0];
  const float* emb  = (const float*)d_in[1];
  const float* lp0  = (const float*)d_in[2];
  const float* Wx   = (const float*)d_in[3];
  const float* wxt  = (const float*)d_in[4];
  const float* bx   = (const float*)d_in[5];
  const float* Wh   = (const float*)d_in[6];
  const float* wht  = (const float*)d_in[7];
  const float* bh   = (const float*)d_in[8];
  const float* W2   = (const float*)d_in[9];
  const float* b2   = (const float*)d_in[10];
  float* out = (float*)d_out;

  char* ws = (char*)d_ws;
  float* hbt          = (float*)ws;            // 5*16*128 f32 = 40960 B
  float* cv           = (float*)(ws + 40960);  // 128 f32     = 512 B
  unsigned short* wxb = (unsigned short*)(ws + 41472); // 16384 bf16 = 32768 B
  unsigned short* w2b = (unsigned short*)(ws + 74240); // 16384 bf16 = 32768 B

  cnf_prep<<<19, 256, 0, stream>>>(h, Wx, wxt, bx, Wh, wht, bh, W2, hbt, cv, wxb, w2b);
  cnf_main<<<2500, 256, 0, stream>>>(emb, lp0, b2, hbt, cv, wxb, w2b, out);
}

// Round 4
// 345.509 us; speedup vs baseline: 1.1125x; 1.1125x over previous
//
#include <hip/hip_runtime.h>

typedef __attribute__((ext_vector_type(8))) short short8;
typedef __attribute__((ext_vector_type(4))) float f32x4;
typedef __attribute__((ext_vector_type(2))) unsigned int u32x2;

#define TTOK 10000

__device__ __forceinline__ unsigned pkbf(float lo, float hi){
  unsigned r;
  asm("v_cvt_pk_bf16_f32 %0, %1, %2" : "=v"(r) : "v"(lo), "v"(hi));
  return r;
}

__device__ __forceinline__ unsigned short f2b(float f){
  unsigned x = __float_as_uint(f);
  unsigned r = (x + 0x7fffu + ((x>>16)&1u)) >> 16; // RNE
  return (unsigned short)r;
}

// ---------------- prep: bf16 weights, hb+t*tw seeds, c vector ----------------
__global__ void cnf_prep(const float* __restrict__ h, const float* __restrict__ Wx,
                         const float* __restrict__ wxt, const float* __restrict__ bx,
                         const float* __restrict__ Wh, const float* __restrict__ wht,
                         const float* __restrict__ bh, const float* __restrict__ W2,
                         float* __restrict__ hbt, float* __restrict__ cv,
                         unsigned short* __restrict__ wxb, unsigned short* __restrict__ w2b)
{
  const int b = blockIdx.x, t = threadIdx.x;
  if (b < 8) {
    for (int i=0;i<8;++i){ int idx = b*2048 + i*256 + t; wxb[idx] = f2b(Wx[idx]); }
  } else if (b < 16) {
    for (int i=0;i<8;++i){ int idx = (b-8)*2048 + i*256 + t; w2b[idx] = f2b(W2[idx]); }
  } else if (b < 18) {
    for (int i=0;i<4;++i){
      int idx = i*256 + t;
      int sb = (b-16)*8 + (idx>>7);
      int j  = idx & 127;
      float a = 0.f;
      for (int e2=0;e2<128;++e2) a += h[sb*128+e2]*Wh[j*128+e2];
      float base = a + bh[j] + bx[j];
      float tw   = wxt[j] + wht[j];
      for (int ti=0; ti<5; ++ti)
        hbt[(ti*16+sb)*128 + j] = base + 0.25f*(float)ti*tw;   // t in {0,.25,.5,.75,1}
    }
  } else {
    if (t < 128){
      float a = 0.f;
      for (int i=0;i<128;++i) a += W2[i*128+t]*Wx[t*128+i];
      cv[t] = a;
    }
  }
}

// ---------------- fused CNF main kernel ----------------
// Block: 256 thr = 4 waves; wave handles 16 rows (one 16-wide N-tile).
// Round-3 lesson: (256,1) let total arch+acc regs cross 256 -> 1 wave/SIMD
// -> occupancy collapse. Fix: shrink demand (zb packed bf16; z is not an
// output, only the divergence is) and pin (256,2) for 2 blocks/CU.
__global__ __launch_bounds__(256, 2) void cnf_main(
    const float* __restrict__ emb, const float* __restrict__ lp0,
    const float* __restrict__ b2g, const float* __restrict__ hbt,
    const float* __restrict__ cg,  const unsigned short* __restrict__ wxb,
    const unsigned short* __restrict__ w2b, float* __restrict__ out)
{
  __shared__ __align__(16) unsigned short sWx[16384];
  __shared__ __align__(16) unsigned short sW2[16384];
  __shared__ __align__(16) float sC[128];
  __shared__ __align__(16) float sB2[128];
  __shared__ __align__(16) float sH[5*2*128];            // hb+t*tw slices for block's <=2 sb values
  __shared__ __align__(16) unsigned short sT[4][1024];   // per-wave transpose buf (2KB)

  const int tid = threadIdx.x;
  const int rowbase = blockIdx.x*64;
  const int sb0 = rowbase/TTOK, sb1 = (rowbase+63)/TTOK;

  // stage weights into LDS with XOR swizzle (row&7)<<4 to kill b128-read bank conflicts
  for (int it=0; it<8; ++it){
    int L = it*4096 + tid*16;          // byte offset, 16B chunk inside one 256B row
    int hrow = L >> 8;
    int dst = L ^ ((hrow&7)<<4);
    *(int4*)((char*)sWx + dst) = *(const int4*)((const char*)wxb + L);
    *(int4*)((char*)sW2 + dst) = *(const int4*)((const char*)w2b + L);
  }
  if (tid < 128) sC[tid] = cg[tid]; else sB2[tid-128] = b2g[tid-128];
  for (int idx = tid; idx < 1280; idx += 256){
    int ti = idx >> 8, r = idx & 255;
    int j = r >> 7, e = r & 127;
    int sb = j ? sb1 : sb0;
    sH[idx] = hbt[(ti*16 + sb)*128 + e];
  }
  __syncthreads();

  const int w = tid>>6, l = tid&63, q = l&15, g = l>>4;
  char* tbB = (char*)&sT[w][0];
  const int cwB = q*16 + 8*(g&1) + 256*(g>>1);  // transpose write base (bytes), + htl*512
  const int crB = g*256 + q*16;                 // transpose read base (bytes), + kcl*1024
  const int wsw = (q&7)<<4;                     // weight-read swizzle
  const int qg  = q*256 + g*16;                 // weight-read lane offset (bytes)

  const int row = rowbase + 16*w + q;
  const int sb  = row/TTOK, tt = row - sb*TTOK;
  const int hsel = (sb == sb0) ? 0 : 128;

  unsigned zbp[8][2];        // z state, packed bf16 (16 VGPRs)
  f32x4 ks[8], wk[8];
  float dlt = 0.f;

  // z0 = emb[t] -> packed bf16 C-layout masters (slot e = 16*ht+4*g+r, col q)
  #pragma unroll
  for (int ht=0; ht<8; ++ht){
    f32x4 e4 = *(const f32x4*)(emb + tt*128 + 16*ht + 4*g);
    zbp[ht][0] = pkbf(e4[0], e4[1]);
    zbp[ht][1] = pkbf(e4[2], e4[3]);
    wk[ht] = (f32x4){0.f,0.f,0.f,0.f};
    ks[ht] = (f32x4){0.f,0.f,0.f,0.f};
  }

  #pragma unroll 1
  for (int se=0; se<8; ++se){
    const int   s    = se>>2, e = se&3;
    const float coef = (e==0)?0.f:((e==3)?0.5f:0.25f); // z_eval = z_base + coef*k_prev
    const float we   = (e==1||e==2)?2.f:1.f;
    const int   ti   = 2*s + ((e==0)?0:((e<3)?1:2));

    // ---- pack z_eval -> LDS transpose (XOR-swizzled) -> bf16 B-frags
    short8 zfr[4];
    #pragma unroll
    for (int hf=0; hf<2; ++hf){
      #pragma unroll
      for (int htl=0; htl<4; ++htl){
        const int ht = 4*hf + htl;
        u32x2 wv;
        if (e==0){
          wv[0] = zbp[ht][0]; wv[1] = zbp[ht][1];   // z_eval == zb, already bf16
        } else {
          float a0 = __uint_as_float(zbp[ht][0]<<16);
          float a1 = __uint_as_float(zbp[ht][0]&0xffff0000u);
          float a2 = __uint_as_float(zbp[ht][1]<<16);
          float a3 = __uint_as_float(zbp[ht][1]&0xffff0000u);
          float v0 = fmaf(coef, wk[ht][0], a0);
          float v1 = fmaf(coef, wk[ht][1], a1);
          float v2 = fmaf(coef, wk[ht][2], a2);
          float v3 = fmaf(coef, wk[ht][3], a3);
          wv[0] = pkbf(v0,v1); wv[1] = pkbf(v2,v3);
        }
        int W = htl*512 + cwB;
        W ^= ((W>>8)&7)<<4;
        *(u32x2*)(tbB + W) = wv;
      }
      #pragma unroll
      for (int kcl=0; kcl<2; ++kcl){
        int R = kcl*1024 + crB;
        R ^= ((R>>8)&7)<<4;
        zfr[2*hf+kcl] = *(const short8*)(tbB + R);
      }
    }

    // ---- seed acc with hb + t*tw (LDS slice)
    {
      const float* hb = &sH[ti*256 + hsel + 4*g];
      #pragma unroll
      for (int ht=0; ht<8; ++ht)
        wk[ht] = *(const f32x4*)(hb + 16*ht);
    }

    // ---- matmul1: pre = Wx . zT
    #pragma unroll
    for (int kc=0; kc<4; ++kc){
      #pragma unroll
      for (int ht=0; ht<8; ++ht){
        const int off = (ht*4096 + kc*64 + qg) ^ wsw;
        short8 af = *(const short8*)((const char*)sWx + off);
        wk[ht] = __builtin_amdgcn_mfma_f32_16x16x32_bf16(af, zfr[kc], wk[ht], 0,0,0);
      }
    }

    // ---- elementwise: softplus -> bf16 frags (via swizzled LDS transpose), sigmoid*c -> div
    short8 sfr[4];
    float dv = 0.f;
    #pragma unroll
    for (int hf=0; hf<2; ++hf){
      #pragma unroll
      for (int htl=0; htl<4; ++htl){
        const int ht = 4*hf+htl;
        f32x4 cc = *(const f32x4*)(&sC[16*ht + 4*g]);
        float spv[4];
        #pragma unroll
        for (int r=0;r<4;++r){
          float x  = wk[ht][r];
          float ax = __builtin_fabsf(x);
          float ea = __expf(-ax);
          float opa = 1.0f + ea;
          float rc = __builtin_amdgcn_rcpf(opa);
          float lg = __logf(opa);
          spv[r] = fmaxf(x,0.f) + lg;                 // softplus
          float sg = (x >= 0.f) ? rc : ea*rc;         // sigmoid
          dv += sg*cc[r];
        }
        int W = htl*512 + cwB;
        W ^= ((W>>8)&7)<<4;
        u32x2 wv = { pkbf(spv[0],spv[1]), pkbf(spv[2],spv[3]) };
        *(u32x2*)(tbB + W) = wv;
      }
      #pragma unroll
      for (int kcl=0; kcl<2; ++kcl){
        int R = kcl*1024 + crB;
        R ^= ((R>>8)&7)<<4;
        sfr[2*hf+kcl] = *(const short8*)(tbB + R);
      }
    }
    dlt += we*dv;

    // ---- matmul2: dz = W2 . spT  (acc seeded with b2)
    #pragma unroll
    for (int ot=0; ot<8; ++ot)
      wk[ot] = *(const f32x4*)(&sB2[16*ot + 4*g]);
    #pragma unroll
    for (int kc=0; kc<4; ++kc){
      #pragma unroll
      for (int ot=0; ot<8; ++ot){
        const int off = (ot*4096 + kc*64 + qg) ^ wsw;
        short8 af = *(const short8*)((const char*)sW2 + off);
        wk[ot] = __builtin_amdgcn_mfma_f32_16x16x32_bf16(af, sfr[kc], wk[ot], 0,0,0);
      }
    }

    // ---- RK4 accumulate (wk now holds k_e; also feeds next eval's z_eval)
    if (e==0){
      #pragma unroll
      for (int ht=0;ht<8;++ht) ks[ht] = wk[ht];
    } else {
      #pragma unroll
      for (int ht=0;ht<8;++ht) ks[ht] += we*wk[ht];
    }
    if (e==3){
      #pragma unroll
      for (int ht=0;ht<8;++ht){
        float a0 = __uint_as_float(zbp[ht][0]<<16);
        float a1 = __uint_as_float(zbp[ht][0]&0xffff0000u);
        float a2 = __uint_as_float(zbp[ht][1]<<16);
        float a3 = __uint_as_float(zbp[ht][1]&0xffff0000u);
        a0 = fmaf(1.f/12.f, ks[ht][0], a0);
        a1 = fmaf(1.f/12.f, ks[ht][1], a1);
        a2 = fmaf(1.f/12.f, ks[ht][2], a2);
        a3 = fmaf(1.f/12.f, ks[ht][3], a3);
        zbp[ht][0] = pkbf(a0,a1);
        zbp[ht][1] = pkbf(a2,a3);
      }
    }
  }

  // ---- epilogue: reduce div partials over the 4 g-lanes, write log_pz1
  {
    float d = dlt*(1.f/12.f);
    d += __shfl_xor(d, 16, 64);
    d += __shfl_xor(d, 32, 64);
    if (g==0) out[row] = lp0[row] - d;
  }
}

extern "C" void kernel_launch(void* const* d_in, const int* in_sizes, int n_in,
                              void* d_out, int out_size, void* d_ws, size_t ws_size,
                              hipStream_t stream) {
  const float* h    = (const float*)d_in[0];
  const float* emb  = (const float*)d_in[1];
  const float* lp0  = (const float*)d_in[2];
  const float* Wx   = (const float*)d_in[3];
  const float* wxt  = (const float*)d_in[4];
  const float* bx   = (const float*)d_in[5];
  const float* Wh   = (const float*)d_in[6];
  const float* wht  = (const float*)d_in[7];
  const float* bh   = (const float*)d_in[8];
  const float* W2   = (const float*)d_in[9];
  const float* b2   = (const float*)d_in[10];
  float* out = (float*)d_out;

  char* ws = (char*)d_ws;
  float* hbt          = (float*)ws;            // 5*16*128 f32 = 40960 B
  float* cv           = (float*)(ws + 40960);  // 128 f32     = 512 B
  unsigned short* wxb = (unsigned short*)(ws + 41472); // 16384 bf16 = 32768 B
  unsigned short* w2b = (unsigned short*)(ws + 74240); // 16384 bf16 = 32768 B

  cnf_prep<<<19, 256, 0, stream>>>(h, Wx, wxt, bx, Wh, wht, bh, W2, hbt, cv, wxb, w2b);
  cnf_main<<<2500, 256, 0, stream>>>(emb, lp0, b2, hbt, cv, wxb, w2b, out);
}

// Round 5
// 284.866 us; speedup vs baseline: 1.3494x; 1.2129x over previous
//
#include <hip/hip_runtime.h>

typedef __attribute__((ext_vector_type(8))) short short8;
typedef __attribute__((ext_vector_type(4))) float f32x4;
typedef __attribute__((ext_vector_type(2))) unsigned int u32x2;

#define TTOK 10000

__device__ __forceinline__ unsigned pkbf(float lo, float hi){
  unsigned r;
  asm("v_cvt_pk_bf16_f32 %0, %1, %2" : "=v"(r) : "v"(lo), "v"(hi));
  return r;
}
__device__ __forceinline__ float ulo(unsigned p){ return __uint_as_float(p<<16); }
__device__ __forceinline__ float uhi(unsigned p){ return __uint_as_float(p&0xffff0000u); }

__device__ __forceinline__ unsigned short f2b(float f){
  unsigned x = __float_as_uint(f);
  unsigned r = (x + 0x7fffu + ((x>>16)&1u)) >> 16; // RNE
  return (unsigned short)r;
}

// ---------------- prep: bf16 weights, hb+t*tw seeds, c vector ----------------
__global__ void cnf_prep(const float* __restrict__ h, const float* __restrict__ Wx,
                         const float* __restrict__ wxt, const float* __restrict__ bx,
                         const float* __restrict__ Wh, const float* __restrict__ wht,
                         const float* __restrict__ bh, const float* __restrict__ W2,
                         float* __restrict__ hbt, float* __restrict__ cv,
                         unsigned short* __restrict__ wxb, unsigned short* __restrict__ w2b)
{
  const int b = blockIdx.x, t = threadIdx.x;
  if (b < 8) {
    for (int i=0;i<8;++i){ int idx = b*2048 + i*256 + t; wxb[idx] = f2b(Wx[idx]); }
  } else if (b < 16) {
    for (int i=0;i<8;++i){ int idx = (b-8)*2048 + i*256 + t; w2b[idx] = f2b(W2[idx]); }
  } else if (b < 18) {
    for (int i=0;i<4;++i){
      int idx = i*256 + t;
      int sb = (b-16)*8 + (idx>>7);
      int j  = idx & 127;
      float a = 0.f;
      for (int e2=0;e2<128;++e2) a += h[sb*128+e2]*Wh[j*128+e2];
      float base = a + bh[j] + bx[j];
      float tw   = wxt[j] + wht[j];
      for (int ti=0; ti<5; ++ti)
        hbt[(ti*16+sb)*128 + j] = base + 0.25f*(float)ti*tw;   // t in {0,.25,.5,.75,1}
    }
  } else {
    if (t < 128){
      float a = 0.f;
      for (int i=0;i<128;++i) a += W2[i*128+t]*Wx[t*128+i];
      cv[t] = a;
    }
  }
}

// ---------------- fused CNF main kernel ----------------
// Block: 256 thr = 4 waves; wave handles 16 rows (one 16-wide N-tile).
// Register ledger (round 2-4 lesson): at (256,2) the allocator gives 128
// arch + 128 acc; arch demand must be <=128 or it spills ~1KB/thread.
// State: zbp (bf16,16) + ksp (bf16,16) + wk (32) + frags (16) + temps ~ 110.
__global__ __launch_bounds__(256, 2) void cnf_main(
    const float* __restrict__ emb, const float* __restrict__ lp0,
    const float* __restrict__ b2g, const float* __restrict__ hbt,
    const float* __restrict__ cg,  const unsigned short* __restrict__ wxb,
    const unsigned short* __restrict__ w2b, float* __restrict__ out)
{
  __shared__ __align__(16) unsigned short sWx[16384];
  __shared__ __align__(16) unsigned short sW2[16384];
  __shared__ __align__(16) float sC[128];
  __shared__ __align__(16) float sB2[128];
  __shared__ __align__(16) float sH[5*2*128];            // hb+t*tw slices for block's <=2 sb values
  __shared__ __align__(16) unsigned short sT[4][1024];   // per-wave transpose buf (2KB)

  const int tid = threadIdx.x;
  const int rowbase = blockIdx.x*64;
  const int sb0 = rowbase/TTOK, sb1 = (rowbase+63)/TTOK;

  // stage weights into LDS with XOR swizzle (row&7)<<4 to kill b128-read bank conflicts
  for (int it=0; it<8; ++it){
    int L = it*4096 + tid*16;          // byte offset, 16B chunk inside one 256B row
    int hrow = L >> 8;
    int dst = L ^ ((hrow&7)<<4);
    *(int4*)((char*)sWx + dst) = *(const int4*)((const char*)wxb + L);
    *(int4*)((char*)sW2 + dst) = *(const int4*)((const char*)w2b + L);
  }
  if (tid < 128) sC[tid] = cg[tid]; else sB2[tid-128] = b2g[tid-128];
  for (int idx = tid; idx < 1280; idx += 256){
    int ti = idx >> 8, r = idx & 255;
    int j = r >> 7, e = r & 127;
    int sb = j ? sb1 : sb0;
    sH[idx] = hbt[(ti*16 + sb)*128 + e];
  }
  __syncthreads();

  const int w = tid>>6, l = tid&63, q = l&15, g = l>>4;
  char* tbB = (char*)&sT[w][0];
  const int cwB = q*16 + 8*(g&1) + 256*(g>>1);  // transpose write base (bytes), + htl*512
  const int crB = g*256 + q*16;                 // transpose read base (bytes), + kcl*1024
  const int wsw = (q&7)<<4;                     // weight-read swizzle
  const int qg  = q*256 + g*16;                 // weight-read lane offset (bytes)

  const int row = rowbase + 16*w + q;
  const int sb  = row/TTOK, tt = row - sb*TTOK;
  const int hsel = (sb == sb0) ? 0 : 128;

  unsigned zbp[8][2];        // z state, packed bf16 (16 VGPRs)
  unsigned ksp[8][2];        // RK4 running sum, packed bf16 (16 VGPRs)
  f32x4 wk[8];
  float dlt = 0.f;

  // z0 = emb[t] -> packed bf16 C-layout masters (slot e = 16*ht+4*g+r, col q)
  #pragma unroll
  for (int ht=0; ht<8; ++ht){
    f32x4 e4 = *(const f32x4*)(emb + tt*128 + 16*ht + 4*g);
    zbp[ht][0] = pkbf(e4[0], e4[1]);
    zbp[ht][1] = pkbf(e4[2], e4[3]);
    wk[ht] = (f32x4){0.f,0.f,0.f,0.f};
    ksp[ht][0] = 0u; ksp[ht][1] = 0u;
  }

  #pragma unroll 1
  for (int se=0; se<8; ++se){
    const int   s    = se>>2, e = se&3;
    const float coef = (e==0)?0.f:((e==3)?0.5f:0.25f); // z_eval = z_base + coef*k_prev
    const float we   = (e==1||e==2)?2.f:1.f;
    const int   ti   = 2*s + ((e==0)?0:((e<3)?1:2));

    // ---- pack z_eval -> LDS transpose (XOR-swizzled) -> bf16 B-frags
    short8 zfr[4];
    #pragma unroll
    for (int hf=0; hf<2; ++hf){
      #pragma unroll
      for (int htl=0; htl<4; ++htl){
        const int ht = 4*hf + htl;
        u32x2 wv;
        if (e==0){
          wv[0] = zbp[ht][0]; wv[1] = zbp[ht][1];   // z_eval == zb, already bf16
        } else {
          float v0 = fmaf(coef, wk[ht][0], ulo(zbp[ht][0]));
          float v1 = fmaf(coef, wk[ht][1], uhi(zbp[ht][0]));
          float v2 = fmaf(coef, wk[ht][2], ulo(zbp[ht][1]));
          float v3 = fmaf(coef, wk[ht][3], uhi(zbp[ht][1]));
          wv[0] = pkbf(v0,v1); wv[1] = pkbf(v2,v3);
        }
        int W = htl*512 + cwB;
        W ^= ((W>>8)&7)<<4;
        *(u32x2*)(tbB + W) = wv;
      }
      #pragma unroll
      for (int kcl=0; kcl<2; ++kcl){
        int R = kcl*1024 + crB;
        R ^= ((R>>8)&7)<<4;
        zfr[2*hf+kcl] = *(const short8*)(tbB + R);
      }
    }

    // ---- seed acc with hb + t*tw (LDS slice)
    {
      const float* hb = &sH[ti*256 + hsel + 4*g];
      #pragma unroll
      for (int ht=0; ht<8; ++ht)
        wk[ht] = *(const f32x4*)(hb + 16*ht);
    }

    // ---- matmul1: pre = Wx . zT
    #pragma unroll
    for (int kc=0; kc<4; ++kc){
      #pragma unroll
      for (int ht=0; ht<8; ++ht){
        const int off = (ht*4096 + kc*64 + qg) ^ wsw;
        short8 af = *(const short8*)((const char*)sWx + off);
        wk[ht] = __builtin_amdgcn_mfma_f32_16x16x32_bf16(af, zfr[kc], wk[ht], 0,0,0);
      }
    }

    // ---- elementwise: softplus -> bf16 frags (via swizzled LDS transpose), sigmoid*c -> div
    short8 sfr[4];
    float dv = 0.f;
    #pragma unroll
    for (int hf=0; hf<2; ++hf){
      #pragma unroll
      for (int htl=0; htl<4; ++htl){
        const int ht = 4*hf+htl;
        f32x4 cc = *(const f32x4*)(&sC[16*ht + 4*g]);
        float spv[4];
        #pragma unroll
        for (int r=0;r<4;++r){
          float x  = wk[ht][r];
          float ax = __builtin_fabsf(x);
          float ea = __expf(-ax);
          float opa = 1.0f + ea;
          float rc = __builtin_amdgcn_rcpf(opa);
          float lg = __logf(opa);
          spv[r] = fmaxf(x,0.f) + lg;                 // softplus
          float sg = (x >= 0.f) ? rc : ea*rc;         // sigmoid
          dv += sg*cc[r];
        }
        int W = htl*512 + cwB;
        W ^= ((W>>8)&7)<<4;
        u32x2 wv = { pkbf(spv[0],spv[1]), pkbf(spv[2],spv[3]) };
        *(u32x2*)(tbB + W) = wv;
      }
      #pragma unroll
      for (int kcl=0; kcl<2; ++kcl){
        int R = kcl*1024 + crB;
        R ^= ((R>>8)&7)<<4;
        sfr[2*hf+kcl] = *(const short8*)(tbB + R);
      }
    }
    dlt += we*dv;

    // ---- matmul2: dz = W2 . spT  (acc seeded with b2)
    #pragma unroll
    for (int ot=0; ot<8; ++ot)
      wk[ot] = *(const f32x4*)(&sB2[16*ot + 4*g]);
    #pragma unroll
    for (int kc=0; kc<4; ++kc){
      #pragma unroll
      for (int ot=0; ot<8; ++ot){
        const int off = (ot*4096 + kc*64 + qg) ^ wsw;
        short8 af = *(const short8*)((const char*)sW2 + off);
        wk[ot] = __builtin_amdgcn_mfma_f32_16x16x32_bf16(af, sfr[kc], wk[ot], 0,0,0);
      }
    }

    // ---- RK4 accumulate into packed bf16 ksp (wk = k_e; feeds next z_eval too)
    if (e==0){
      #pragma unroll
      for (int ht=0;ht<8;++ht){
        ksp[ht][0] = pkbf(wk[ht][0], wk[ht][1]);
        ksp[ht][1] = pkbf(wk[ht][2], wk[ht][3]);
      }
    } else if (e<3){
      #pragma unroll
      for (int ht=0;ht<8;++ht){
        float a0 = fmaf(we, wk[ht][0], ulo(ksp[ht][0]));
        float a1 = fmaf(we, wk[ht][1], uhi(ksp[ht][0]));
        float a2 = fmaf(we, wk[ht][2], ulo(ksp[ht][1]));
        float a3 = fmaf(we, wk[ht][3], uhi(ksp[ht][1]));
        ksp[ht][0] = pkbf(a0,a1);
        ksp[ht][1] = pkbf(a2,a3);
      }
    } else {
      // z += (ks + k4)/12, straight into packed z state
      #pragma unroll
      for (int ht=0;ht<8;++ht){
        float a0 = fmaf(1.f/12.f, ulo(ksp[ht][0]) + wk[ht][0], ulo(zbp[ht][0]));
        float a1 = fmaf(1.f/12.f, uhi(ksp[ht][0]) + wk[ht][1], uhi(zbp[ht][0]));
        float a2 = fmaf(1.f/12.f, ulo(ksp[ht][1]) + wk[ht][2], ulo(zbp[ht][1]));
        float a3 = fmaf(1.f/12.f, uhi(ksp[ht][1]) + wk[ht][3], uhi(zbp[ht][1]));
        zbp[ht][0] = pkbf(a0,a1);
        zbp[ht][1] = pkbf(a2,a3);
      }
    }
  }

  // ---- epilogue: reduce div partials over the 4 g-lanes, write log_pz1
  {
    float d = dlt*(1.f/12.f);
    d += __shfl_xor(d, 16, 64);
    d += __shfl_xor(d, 32, 64);
    if (g==0) out[row] = lp0[row] - d;
  }
}

extern "C" void kernel_launch(void* const* d_in, const int* in_sizes, int n_in,
                              void* d_out, int out_size, void* d_ws, size_t ws_size,
                              hipStream_t stream) {
  const float* h    = (const float*)d_in[0];
  const float* emb  = (const float*)d_in[1];
  const float* lp0  = (const float*)d_in[2];
  const float* Wx   = (const float*)d_in[3];
  const float* wxt  = (const float*)d_in[4];
  const float* bx   = (const float*)d_in[5];
  const float* Wh   = (const float*)d_in[6];
  const float* wht  = (const float*)d_in[7];
  const float* bh   = (const float*)d_in[8];
  const float* W2   = (const float*)d_in[9];
  const float* b2   = (const float*)d_in[10];
  float* out = (float*)d_out;

  char* ws = (char*)d_ws;
  float* hbt          = (float*)ws;            // 5*16*128 f32 = 40960 B
  float* cv           = (float*)(ws + 40960);  // 128 f32     = 512 B
  unsigned short* wxb = (unsigned short*)(ws + 41472); // 16384 bf16 = 32768 B
  unsigned short* w2b = (unsigned short*)(ws + 74240); // 16384 bf16 = 32768 B

  cnf_prep<<<19, 256, 0, stream>>>(h, Wx, wxt, bx, Wh, wht, bh, W2, hbt, cv, wxb, w2b);
  cnf_main<<<2500, 256, 0, stream>>>(emb, lp0, b2, hbt, cv, wxb, w2b, out);
}

// Round 6
// 262.752 us; speedup vs baseline: 1.4630x; 1.0842x over previous
//
#include <hip/hip_runtime.h>

typedef __attribute__((ext_vector_type(8))) short short8;
typedef __attribute__((ext_vector_type(4))) float f32x4;
typedef __attribute__((ext_vector_type(2))) unsigned int u32x2;

#define TTOK 10000
#define SBAR() __builtin_amdgcn_sched_barrier(0)

__device__ __forceinline__ unsigned pkbf(float lo, float hi){
  unsigned r;
  asm("v_cvt_pk_bf16_f32 %0, %1, %2" : "=v"(r) : "v"(lo), "v"(hi));
  return r;
}
__device__ __forceinline__ float ulo(unsigned p){ return __uint_as_float(p<<16); }
__device__ __forceinline__ float uhi(unsigned p){ return __uint_as_float(p&0xffff0000u); }

__device__ __forceinline__ unsigned short f2b(float f){
  unsigned x = __float_as_uint(f);
  unsigned r = (x + 0x7fffu + ((x>>16)&1u)) >> 16; // RNE
  return (unsigned short)r;
}

// ---------------- prep: bf16 weights, hb+t*tw seeds, c vector ----------------
__global__ void cnf_prep(const float* __restrict__ h, const float* __restrict__ Wx,
                         const float* __restrict__ wxt, const float* __restrict__ bx,
                         const float* __restrict__ Wh, const float* __restrict__ wht,
                         const float* __restrict__ bh, const float* __restrict__ W2,
                         float* __restrict__ hbt, float* __restrict__ cv,
                         unsigned short* __restrict__ wxb, unsigned short* __restrict__ w2b)
{
  const int b = blockIdx.x, t = threadIdx.x;
  if (b < 8) {
    for (int i=0;i<8;++i){ int idx = b*2048 + i*256 + t; wxb[idx] = f2b(Wx[idx]); }
  } else if (b < 16) {
    for (int i=0;i<8;++i){ int idx = (b-8)*2048 + i*256 + t; w2b[idx] = f2b(W2[idx]); }
  } else if (b < 18) {
    for (int i=0;i<4;++i){
      int idx = i*256 + t;
      int sb = (b-16)*8 + (idx>>7);
      int j  = idx & 127;
      float a = 0.f;
      for (int e2=0;e2<128;++e2) a += h[sb*128+e2]*Wh[j*128+e2];
      float base = a + bh[j] + bx[j];
      float tw   = wxt[j] + wht[j];
      for (int ti=0; ti<5; ++ti)
        hbt[(ti*16+sb)*128 + j] = base + 0.25f*(float)ti*tw;   // t in {0,.25,.5,.75,1}
    }
  } else {
    if (t < 128){
      float a = 0.f;
      for (int i=0;i<128;++i) a += W2[i*128+t]*Wx[t*128+i];
      cv[t] = a;
    }
  }
}

// ---------------- fused CNF main kernel ----------------
// Block: 256 thr = 4 waves; wave handles 16 rows (one 16-wide N-tile).
// Round 2-5 lesson: at (256,2) arch regs cap at 128; the *scheduler's*
// cross-phase hoisting (not static demand ~110) pushed live sets past 128
// and spilled ~740B/thread. Fix: sched_barrier(0) fences between phases to
// bound pressure to single-phase levels; each phase has ample internal ILP.
__global__ __launch_bounds__(256, 2) void cnf_main(
    const float* __restrict__ emb, const float* __restrict__ lp0,
    const float* __restrict__ b2g, const float* __restrict__ hbt,
    const float* __restrict__ cg,  const unsigned short* __restrict__ wxb,
    const unsigned short* __restrict__ w2b, float* __restrict__ out)
{
  __shared__ __align__(16) unsigned short sWx[16384];
  __shared__ __align__(16) unsigned short sW2[16384];
  __shared__ __align__(16) float sC[128];
  __shared__ __align__(16) float sB2[128];
  __shared__ __align__(16) float sH[5*2*128];            // hb+t*tw slices for block's <=2 sb values
  __shared__ __align__(16) unsigned short sT[4][1024];   // per-wave transpose buf (2KB)

  const int tid = threadIdx.x;
  const int rowbase = blockIdx.x*64;
  const int sb0 = rowbase/TTOK, sb1 = (rowbase+63)/TTOK;

  // stage weights into LDS with XOR swizzle (row&7)<<4 to kill b128-read bank conflicts
  for (int it=0; it<8; ++it){
    int L = it*4096 + tid*16;          // byte offset, 16B chunk inside one 256B row
    int hrow = L >> 8;
    int dst = L ^ ((hrow&7)<<4);
    *(int4*)((char*)sWx + dst) = *(const int4*)((const char*)wxb + L);
    *(int4*)((char*)sW2 + dst) = *(const int4*)((const char*)w2b + L);
  }
  if (tid < 128) sC[tid] = cg[tid]; else sB2[tid-128] = b2g[tid-128];
  for (int idx = tid; idx < 1280; idx += 256){
    int ti = idx >> 8, r = idx & 255;
    int j = r >> 7, e = r & 127;
    int sb = j ? sb1 : sb0;
    sH[idx] = hbt[(ti*16 + sb)*128 + e];
  }
  __syncthreads();

  const int w = tid>>6, l = tid&63, q = l&15, g = l>>4;
  char* tbB = (char*)&sT[w][0];
  const int cwB = q*16 + 8*(g&1) + 256*(g>>1);  // transpose write base (bytes), + htl*512
  const int crB = g*256 + q*16;                 // transpose read base (bytes), + kcl*1024
  const int wsw = (q&7)<<4;                     // weight-read swizzle
  const int qg  = q*256 + g*16;                 // weight-read lane offset (bytes)

  const int row = rowbase + 16*w + q;
  const int sb  = row/TTOK, tt = row - sb*TTOK;
  const int hsel = (sb == sb0) ? 0 : 128;

  unsigned zbp[8][2];        // z state, packed bf16 (16 VGPRs)
  unsigned ksp[8][2];        // RK4 running sum, packed bf16 (16 VGPRs)
  f32x4 wk[8];
  float dlt = 0.f;

  // z0 = emb[t] -> packed bf16 C-layout masters (slot e = 16*ht+4*g+r, col q)
  #pragma unroll
  for (int ht=0; ht<8; ++ht){
    f32x4 e4 = *(const f32x4*)(emb + tt*128 + 16*ht + 4*g);
    zbp[ht][0] = pkbf(e4[0], e4[1]);
    zbp[ht][1] = pkbf(e4[2], e4[3]);
    wk[ht] = (f32x4){0.f,0.f,0.f,0.f};
    ksp[ht][0] = 0u; ksp[ht][1] = 0u;
  }

  #pragma unroll 1
  for (int se=0; se<8; ++se){
    const int   s    = se>>2, e = se&3;
    const float coef = (e==0)?0.f:((e==3)?0.5f:0.25f); // z_eval = z_base + coef*k_prev
    const float we   = (e==1||e==2)?2.f:1.f;
    const int   ti   = 2*s + ((e==0)?0:((e<3)?1:2));

    // ---- phase 1: pack z_eval -> LDS transpose (XOR-swizzled) -> bf16 B-frags
    short8 zfr[4];
    #pragma unroll
    for (int hf=0; hf<2; ++hf){
      #pragma unroll
      for (int htl=0; htl<4; ++htl){
        const int ht = 4*hf + htl;
        u32x2 wv;
        if (e==0){
          wv[0] = zbp[ht][0]; wv[1] = zbp[ht][1];   // z_eval == zb, already bf16
        } else {
          float v0 = fmaf(coef, wk[ht][0], ulo(zbp[ht][0]));
          float v1 = fmaf(coef, wk[ht][1], uhi(zbp[ht][0]));
          float v2 = fmaf(coef, wk[ht][2], ulo(zbp[ht][1]));
          float v3 = fmaf(coef, wk[ht][3], uhi(zbp[ht][1]));
          wv[0] = pkbf(v0,v1); wv[1] = pkbf(v2,v3);
        }
        int W = htl*512 + cwB;
        W ^= ((W>>8)&7)<<4;
        *(u32x2*)(tbB + W) = wv;
      }
      #pragma unroll
      for (int kcl=0; kcl<2; ++kcl){
        int R = kcl*1024 + crB;
        R ^= ((R>>8)&7)<<4;
        zfr[2*hf+kcl] = *(const short8*)(tbB + R);
      }
    }
    SBAR();

    // ---- phase 2: seed acc with hb + t*tw (LDS slice)
    {
      const float* hb = &sH[ti*256 + hsel + 4*g];
      #pragma unroll
      for (int ht=0; ht<8; ++ht)
        wk[ht] = *(const f32x4*)(hb + 16*ht);
    }
    SBAR();

    // ---- phase 3: matmul1: pre = Wx . zT
    #pragma unroll
    for (int kc=0; kc<4; ++kc){
      #pragma unroll
      for (int ht=0; ht<8; ++ht){
        const int off = (ht*4096 + kc*64 + qg) ^ wsw;
        short8 af = *(const short8*)((const char*)sWx + off);
        wk[ht] = __builtin_amdgcn_mfma_f32_16x16x32_bf16(af, zfr[kc], wk[ht], 0,0,0);
      }
    }
    SBAR();

    // ---- phase 4: softplus -> bf16 frags (via swizzled LDS transpose), sigmoid*c -> div
    short8 sfr[4];
    float dv = 0.f;
    #pragma unroll
    for (int hf=0; hf<2; ++hf){
      #pragma unroll
      for (int htl=0; htl<4; ++htl){
        const int ht = 4*hf+htl;
        f32x4 cc = *(const f32x4*)(&sC[16*ht + 4*g]);
        float spv[4];
        #pragma unroll
        for (int r=0;r<4;++r){
          float x  = wk[ht][r];
          float ax = __builtin_fabsf(x);
          float ea = __expf(-ax);
          float opa = 1.0f + ea;
          float rc = __builtin_amdgcn_rcpf(opa);
          float lg = __logf(opa);
          spv[r] = fmaxf(x,0.f) + lg;                 // softplus
          float sg = (x >= 0.f) ? rc : ea*rc;         // sigmoid
          dv += sg*cc[r];
        }
        int W = htl*512 + cwB;
        W ^= ((W>>8)&7)<<4;
        u32x2 wv = { pkbf(spv[0],spv[1]), pkbf(spv[2],spv[3]) };
        *(u32x2*)(tbB + W) = wv;
      }
      #pragma unroll
      for (int kcl=0; kcl<2; ++kcl){
        int R = kcl*1024 + crB;
        R ^= ((R>>8)&7)<<4;
        sfr[2*hf+kcl] = *(const short8*)(tbB + R);
      }
    }
    dlt += we*dv;
    SBAR();

    // ---- phase 5: matmul2: dz = W2 . spT  (acc seeded with b2)
    #pragma unroll
    for (int ot=0; ot<8; ++ot)
      wk[ot] = *(const f32x4*)(&sB2[16*ot + 4*g]);
    SBAR();
    #pragma unroll
    for (int kc=0; kc<4; ++kc){
      #pragma unroll
      for (int ot=0; ot<8; ++ot){
        const int off = (ot*4096 + kc*64 + qg) ^ wsw;
        short8 af = *(const short8*)((const char*)sW2 + off);
        wk[ot] = __builtin_amdgcn_mfma_f32_16x16x32_bf16(af, sfr[kc], wk[ot], 0,0,0);
      }
    }
    SBAR();

    // ---- phase 6: RK4 accumulate into packed bf16 ksp (wk = k_e; feeds next z_eval too)
    if (e==0){
      #pragma unroll
      for (int ht=0;ht<8;++ht){
        ksp[ht][0] = pkbf(wk[ht][0], wk[ht][1]);
        ksp[ht][1] = pkbf(wk[ht][2], wk[ht][3]);
      }
    } else if (e<3){
      #pragma unroll
      for (int ht=0;ht<8;++ht){
        float a0 = fmaf(we, wk[ht][0], ulo(ksp[ht][0]));
        float a1 = fmaf(we, wk[ht][1], uhi(ksp[ht][0]));
        float a2 = fmaf(we, wk[ht][2], ulo(ksp[ht][1]));
        float a3 = fmaf(we, wk[ht][3], uhi(ksp[ht][1]));
        ksp[ht][0] = pkbf(a0,a1);
        ksp[ht][1] = pkbf(a2,a3);
      }
    } else {
      // z += (ks + k4)/12, straight into packed z state
      #pragma unroll
      for (int ht=0;ht<8;++ht){
        float a0 = fmaf(1.f/12.f, ulo(ksp[ht][0]) + wk[ht][0], ulo(zbp[ht][0]));
        float a1 = fmaf(1.f/12.f, uhi(ksp[ht][0]) + wk[ht][1], uhi(zbp[ht][0]));
        float a2 = fmaf(1.f/12.f, ulo(ksp[ht][1]) + wk[ht][2], ulo(zbp[ht][1]));
        float a3 = fmaf(1.f/12.f, uhi(ksp[ht][1]) + wk[ht][3], uhi(zbp[ht][1]));
        zbp[ht][0] = pkbf(a0,a1);
        zbp[ht][1] = pkbf(a2,a3);
      }
    }
    SBAR();
  }

  // ---- epilogue: reduce div partials over the 4 g-lanes, write log_pz1
  {
    float d = dlt*(1.f/12.f);
    d += __shfl_xor(d, 16, 64);
    d += __shfl_xor(d, 32, 64);
    if (g==0) out[row] = lp0[row] - d;
  }
}

extern "C" void kernel_launch(void* const* d_in, const int* in_sizes, int n_in,
                              void* d_out, int out_size, void* d_ws, size_t ws_size,
                              hipStream_t stream) {
  const float* h    = (const float*)d_in[0];
  const float* emb  = (const float*)d_in[1];
  const float* lp0  = (const float*)d_in[2];
  const float* Wx   = (const float*)d_in[3];
  const float* wxt  = (const float*)d_in[4];
  const float* bx   = (const float*)d_in[5];
  const float* Wh   = (const float*)d_in[6];
  const float* wht  = (const float*)d_in[7];
  const float* bh   = (const float*)d_in[8];
  const float* W2   = (const float*)d_in[9];
  const float* b2   = (const float*)d_in[10];
  float* out = (float*)d_out;

  char* ws = (char*)d_ws;
  float* hbt          = (float*)ws;            // 5*16*128 f32 = 40960 B
  float* cv           = (float*)(ws + 40960);  // 128 f32     = 512 B
  unsigned short* wxb = (unsigned short*)(ws + 41472); // 16384 bf16 = 32768 B
  unsigned short* w2b = (unsigned short*)(ws + 74240); // 16384 bf16 = 32768 B

  cnf_prep<<<19, 256, 0, stream>>>(h, Wx, wxt, bx, Wh, wht, bh, W2, hbt, cv, wxb, w2b);
  cnf_main<<<2500, 256, 0, stream>>>(emb, lp0, b2, hbt, cv, wxb, w2b, out);
}

// Round 7
// 257.606 us; speedup vs baseline: 1.4922x; 1.0200x over previous
//
#include <hip/hip_runtime.h>

typedef __attribute__((ext_vector_type(8))) short short8;
typedef __attribute__((ext_vector_type(4))) float f32x4;
typedef __attribute__((ext_vector_type(2))) unsigned int u32x2;

#define TTOK 10000
#define SBAR() __builtin_amdgcn_sched_barrier(0)

__device__ __forceinline__ unsigned pkbf(float lo, float hi){
  unsigned r;
  asm("v_cvt_pk_bf16_f32 %0, %1, %2" : "=v"(r) : "v"(lo), "v"(hi));
  return r;
}
__device__ __forceinline__ float ulo(unsigned p){ return __uint_as_float(p<<16); }
__device__ __forceinline__ float uhi(unsigned p){ return __uint_as_float(p&0xffff0000u); }

__device__ __forceinline__ unsigned short f2b(float f){
  unsigned x = __float_as_uint(f);
  unsigned r = (x + 0x7fffu + ((x>>16)&1u)) >> 16; // RNE
  return (unsigned short)r;
}

// ---------------- prep: bf16 weights, hb+t*tw seeds, c vector ----------------
__global__ void cnf_prep(const float* __restrict__ h, const float* __restrict__ Wx,
                         const float* __restrict__ wxt, const float* __restrict__ bx,
                         const float* __restrict__ Wh, const float* __restrict__ wht,
                         const float* __restrict__ bh, const float* __restrict__ W2,
                         float* __restrict__ hbt, float* __restrict__ cv,
                         unsigned short* __restrict__ wxb, unsigned short* __restrict__ w2b)
{
  const int b = blockIdx.x, t = threadIdx.x;
  if (b < 8) {
    for (int i=0;i<8;++i){ int idx = b*2048 + i*256 + t; wxb[idx] = f2b(Wx[idx]); }
  } else if (b < 16) {
    for (int i=0;i<8;++i){ int idx = (b-8)*2048 + i*256 + t; w2b[idx] = f2b(W2[idx]); }
  } else if (b < 18) {
    for (int i=0;i<4;++i){
      int idx = i*256 + t;
      int sb = (b-16)*8 + (idx>>7);
      int j  = idx & 127;
      float a = 0.f;
      for (int e2=0;e2<128;++e2) a += h[sb*128+e2]*Wh[j*128+e2];
      float base = a + bh[j] + bx[j];
      float tw   = wxt[j] + wht[j];
      for (int ti=0; ti<5; ++ti)
        hbt[(ti*16+sb)*128 + j] = base + 0.25f*(float)ti*tw;   // t in {0,.25,.5,.75,1}
    }
  } else {
    if (t < 128){
      float a = 0.f;
      for (int i=0;i<128;++i) a += W2[i*128+t]*Wx[t*128+i];
      cv[t] = a;
    }
  }
}

// ---------------- fused CNF main kernel ----------------
// Block: 256 thr = 4 waves; wave handles 16 rows (one 16-wide N-tile).
// Rounds 2-6 lesson: at (256,2) the budget is 128 arch + 128 acc per wave.
// Static arch demand ~70 is fine; the killer was the scheduler hoisting a
// whole matmul phase's 32 weight frags (128 VGPRs) ahead of the MFMAs.
// Fix: sched_barrier at kc granularity inside matmuls (max 8 frags = 32
// VGPRs in flight) + per-hf fences in pack/softplus phases.
__global__ __launch_bounds__(256, 2) void cnf_main(
    const float* __restrict__ emb, const float* __restrict__ lp0,
    const float* __restrict__ b2g, const float* __restrict__ hbt,
    const float* __restrict__ cg,  const unsigned short* __restrict__ wxb,
    const unsigned short* __restrict__ w2b, float* __restrict__ out)
{
  __shared__ __align__(16) unsigned short sWx[16384];
  __shared__ __align__(16) unsigned short sW2[16384];
  __shared__ __align__(16) float sC[128];
  __shared__ __align__(16) float sB2[128];
  __shared__ __align__(16) float sH[5*2*128];            // hb+t*tw slices for block's <=2 sb values
  __shared__ __align__(16) unsigned short sT[4][1024];   // per-wave transpose buf (2KB)

  const int tid = threadIdx.x;
  const int rowbase = blockIdx.x*64;
  const int sb0 = rowbase/TTOK, sb1 = (rowbase+63)/TTOK;

  // stage weights into LDS with XOR swizzle (row&7)<<4 to kill b128-read bank conflicts
  for (int it=0; it<8; ++it){
    int L = it*4096 + tid*16;          // byte offset, 16B chunk inside one 256B row
    int hrow = L >> 8;
    int dst = L ^ ((hrow&7)<<4);
    *(int4*)((char*)sWx + dst) = *(const int4*)((const char*)wxb + L);
    *(int4*)((char*)sW2 + dst) = *(const int4*)((const char*)w2b + L);
  }
  if (tid < 128) sC[tid] = cg[tid]; else sB2[tid-128] = b2g[tid-128];
  for (int idx = tid; idx < 1280; idx += 256){
    int ti = idx >> 8, r = idx & 255;
    int j = r >> 7, e = r & 127;
    int sb = j ? sb1 : sb0;
    sH[idx] = hbt[(ti*16 + sb)*128 + e];
  }
  __syncthreads();

  const int w = tid>>6, l = tid&63, q = l&15, g = l>>4;
  char* tbB = (char*)&sT[w][0];
  const int cwB = q*16 + 8*(g&1) + 256*(g>>1);  // transpose write base (bytes), + htl*512
  const int crB = g*256 + q*16;                 // transpose read base (bytes), + kcl*1024
  const int wsw = (q&7)<<4;                     // weight-read swizzle
  const int qg  = q*256 + g*16;                 // weight-read lane offset (bytes)

  const int row = rowbase + 16*w + q;
  const int sb  = row/TTOK, tt = row - sb*TTOK;
  const int hsel = (sb == sb0) ? 0 : 128;

  unsigned zbp[8][2];        // z state, packed bf16 (16 VGPRs)
  unsigned ksp[8][2];        // RK4 running sum, packed bf16 (16 VGPRs)
  f32x4 wk[8];
  float dlt = 0.f;

  // z0 = emb[t] -> packed bf16 C-layout masters (slot e = 16*ht+4*g+r, col q)
  #pragma unroll
  for (int ht=0; ht<8; ++ht){
    f32x4 e4 = *(const f32x4*)(emb + tt*128 + 16*ht + 4*g);
    zbp[ht][0] = pkbf(e4[0], e4[1]);
    zbp[ht][1] = pkbf(e4[2], e4[3]);
    wk[ht] = (f32x4){0.f,0.f,0.f,0.f};
    ksp[ht][0] = 0u; ksp[ht][1] = 0u;
  }

  #pragma unroll 1
  for (int se=0; se<8; ++se){
    const int   s    = se>>2, e = se&3;
    const float coef = (e==0)?0.f:((e==3)?0.5f:0.25f); // z_eval = z_base + coef*k_prev
    const float we   = (e==1||e==2)?2.f:1.f;
    const int   ti   = 2*s + ((e==0)?0:((e<3)?1:2));

    // ---- phase 1: pack z_eval -> LDS transpose (XOR-swizzled) -> bf16 B-frags
    short8 zfr[4];
    #pragma unroll
    for (int hf=0; hf<2; ++hf){
      #pragma unroll
      for (int htl=0; htl<4; ++htl){
        const int ht = 4*hf + htl;
        u32x2 wv;
        if (e==0){
          wv[0] = zbp[ht][0]; wv[1] = zbp[ht][1];   // z_eval == zb, already bf16
        } else {
          float v0 = fmaf(coef, wk[ht][0], ulo(zbp[ht][0]));
          float v1 = fmaf(coef, wk[ht][1], uhi(zbp[ht][0]));
          float v2 = fmaf(coef, wk[ht][2], ulo(zbp[ht][1]));
          float v3 = fmaf(coef, wk[ht][3], uhi(zbp[ht][1]));
          wv[0] = pkbf(v0,v1); wv[1] = pkbf(v2,v3);
        }
        int W = htl*512 + cwB;
        W ^= ((W>>8)&7)<<4;
        *(u32x2*)(tbB + W) = wv;
      }
      #pragma unroll
      for (int kcl=0; kcl<2; ++kcl){
        int R = kcl*1024 + crB;
        R ^= ((R>>8)&7)<<4;
        zfr[2*hf+kcl] = *(const short8*)(tbB + R);
      }
      SBAR();
    }

    // ---- phase 2: seed acc with hb + t*tw (LDS slice)
    {
      const float* hb = &sH[ti*256 + hsel + 4*g];
      #pragma unroll
      for (int ht=0; ht<8; ++ht)
        wk[ht] = *(const f32x4*)(hb + 16*ht);
    }
    SBAR();

    // ---- phase 3: matmul1: pre = Wx . zT  (kc-fenced: <=8 weight frags in flight)
    #pragma unroll
    for (int kc=0; kc<4; ++kc){
      #pragma unroll
      for (int ht=0; ht<8; ++ht){
        const int off = (ht*4096 + kc*64 + qg) ^ wsw;
        short8 af = *(const short8*)((const char*)sWx + off);
        wk[ht] = __builtin_amdgcn_mfma_f32_16x16x32_bf16(af, zfr[kc], wk[ht], 0,0,0);
      }
      SBAR();
    }

    // ---- phase 4: softplus -> bf16 frags (via swizzled LDS transpose), sigmoid*c -> div
    short8 sfr[4];
    float dv = 0.f;
    #pragma unroll
    for (int hf=0; hf<2; ++hf){
      #pragma unroll
      for (int htl=0; htl<4; ++htl){
        const int ht = 4*hf+htl;
        f32x4 cc = *(const f32x4*)(&sC[16*ht + 4*g]);
        float spv[4];
        #pragma unroll
        for (int r=0;r<4;++r){
          float x  = wk[ht][r];
          float ax = __builtin_fabsf(x);
          float ea = __expf(-ax);
          float opa = 1.0f + ea;
          float rc = __builtin_amdgcn_rcpf(opa);
          float lg = __logf(opa);
          spv[r] = fmaxf(x,0.f) + lg;                 // softplus
          float sg = (x >= 0.f) ? rc : ea*rc;         // sigmoid
          dv += sg*cc[r];
        }
        int W = htl*512 + cwB;
        W ^= ((W>>8)&7)<<4;
        u32x2 wv = { pkbf(spv[0],spv[1]), pkbf(spv[2],spv[3]) };
        *(u32x2*)(tbB + W) = wv;
      }
      #pragma unroll
      for (int kcl=0; kcl<2; ++kcl){
        int R = kcl*1024 + crB;
        R ^= ((R>>8)&7)<<4;
        sfr[2*hf+kcl] = *(const short8*)(tbB + R);
      }
      SBAR();
    }
    dlt += we*dv;

    // ---- phase 5: matmul2: dz = W2 . spT  (acc seeded with b2; kc-fenced)
    #pragma unroll
    for (int ot=0; ot<8; ++ot)
      wk[ot] = *(const f32x4*)(&sB2[16*ot + 4*g]);
    SBAR();
    #pragma unroll
    for (int kc=0; kc<4; ++kc){
      #pragma unroll
      for (int ot=0; ot<8; ++ot){
        const int off = (ot*4096 + kc*64 + qg) ^ wsw;
        short8 af = *(const short8*)((const char*)sW2 + off);
        wk[ot] = __builtin_amdgcn_mfma_f32_16x16x32_bf16(af, sfr[kc], wk[ot], 0,0,0);
      }
      SBAR();
    }

    // ---- phase 6: RK4 accumulate into packed bf16 ksp (wk = k_e; feeds next z_eval too)
    if (e==0){
      #pragma unroll
      for (int ht=0;ht<8;++ht){
        ksp[ht][0] = pkbf(wk[ht][0], wk[ht][1]);
        ksp[ht][1] = pkbf(wk[ht][2], wk[ht][3]);
      }
    } else if (e<3){
      #pragma unroll
      for (int ht=0;ht<8;++ht){
        float a0 = fmaf(we, wk[ht][0], ulo(ksp[ht][0]));
        float a1 = fmaf(we, wk[ht][1], uhi(ksp[ht][0]));
        float a2 = fmaf(we, wk[ht][2], ulo(ksp[ht][1]));
        float a3 = fmaf(we, wk[ht][3], uhi(ksp[ht][1]));
        ksp[ht][0] = pkbf(a0,a1);
        ksp[ht][1] = pkbf(a2,a3);
      }
    } else {
      // z += (ks + k4)/12, straight into packed z state
      #pragma unroll
      for (int ht=0;ht<8;++ht){
        float a0 = fmaf(1.f/12.f, ulo(ksp[ht][0]) + wk[ht][0], ulo(zbp[ht][0]));
        float a1 = fmaf(1.f/12.f, uhi(ksp[ht][0]) + wk[ht][1], uhi(zbp[ht][0]));
        float a2 = fmaf(1.f/12.f, ulo(ksp[ht][1]) + wk[ht][2], ulo(zbp[ht][1]));
        float a3 = fmaf(1.f/12.f, uhi(ksp[ht][1]) + wk[ht][3], uhi(zbp[ht][1]));
        zbp[ht][0] = pkbf(a0,a1);
        zbp[ht][1] = pkbf(a2,a3);
      }
    }
    SBAR();
  }

  // ---- epilogue: reduce div partials over the 4 g-lanes, write log_pz1
  {
    float d = dlt*(1.f/12.f);
    d += __shfl_xor(d, 16, 64);
    d += __shfl_xor(d, 32, 64);
    if (g==0) out[row] = lp0[row] - d;
  }
}

extern "C" void kernel_launch(void* const* d_in, const int* in_sizes, int n_in,
                              void* d_out, int out_size, void* d_ws, size_t ws_size,
                              hipStream_t stream) {
  const float* h    = (const float*)d_in[0];
  const float* emb  = (const float*)d_in[1];
  const float* lp0  = (const float*)d_in[2];
  const float* Wx   = (const float*)d_in[3];
  const float* wxt  = (const float*)d_in[4];
  const float* bx   = (const float*)d_in[5];
  const float* Wh   = (const float*)d_in[6];
  const float* wht  = (const float*)d_in[7];
  const float* bh   = (const float*)d_in[8];
  const float* W2   = (const float*)d_in[9];
  const float* b2   = (const float*)d_in[10];
  float* out = (float*)d_out;

  char* ws = (char*)d_ws;
  float* hbt          = (float*)ws;            // 5*16*128 f32 = 40960 B
  float* cv           = (float*)(ws + 40960);  // 128 f32     = 512 B
  unsigned short* wxb = (unsigned short*)(ws + 41472); // 16384 bf16 = 32768 B
  unsigned short* w2b = (unsigned short*)(ws + 74240); // 16384 bf16 = 32768 B

  cnf_prep<<<19, 256, 0, stream>>>(h, Wx, wxt, bx, Wh, wht, bh, W2, hbt, cv, wxb, w2b);
  cnf_main<<<2500, 256, 0, stream>>>(emb, lp0, b2, hbt, cv, wxb, w2b, out);
}